// Round 7
// baseline (65.938 us; speedup 1.0000x reference)
//
#include <hip/hip_runtime.h>
#include <hip/hip_bf16.h>

#define B_  8
#define L_  4096
#define DH  64

typedef __attribute__((ext_vector_type(8)))  __bf16 bf16x8;
typedef __attribute__((ext_vector_type(16))) float  f32x16;
typedef __attribute__((ext_vector_type(4)))  float  f32x4;
typedef __attribute__((ext_vector_type(8)))  unsigned short u16x8;

// workspace offsets (u16 units unless noted)
#define QW_OFF  0u
#define KW_OFF  2097152u      // Kp: swizzled 32-row K images [8][128][2048]
#define VP_OFF  4194304u      // Vp: slot-permuted V images   [8][128][2048]
#define OP_OFF  6291456u      // bf16 partials [8][32][8][128][64]
#define LP_OFFB 46137344u     // byte offset: f32 l partials [8][32][8][128]

// ---------------------------------------------------------------------------
// Kernel 1: MFMA QKV projection (x cast to bf16, K-dim padded to 96).
//   qo row-major [B*L][64]  (pre-scaled by log2e/sqrt(65))
//   Kp: 32-row tiles, col-chunk c stored at position c^(row&7)   (16B units)
//   Vp: 32-kv tiles [dv][32]: kv -> (m=kv>>4, h=(kv>>2)&1, j=(kv&3)+4*((kv>>3)&1))
//       stored at chunk ((m<<1)|h) ^ ((dv>>1)&3), elem j.
// ---------------------------------------------------------------------------
__global__ __launch_bounds__(256) void qkv_proj(
    const float* __restrict__ x,
    const float* __restrict__ Wq, const float* __restrict__ bq,
    const float* __restrict__ Wk, const float* __restrict__ bk,
    const float* __restrict__ Wv, const float* __restrict__ bv,
    unsigned short* __restrict__ qo,
    unsigned short* __restrict__ Kp,
    unsigned short* __restrict__ Vp)
{
    __shared__ __align__(16) unsigned short xs[64 * 104];
    __shared__ __align__(16) unsigned short wt[64 * 104];
    __shared__ __align__(16) unsigned short bounce[64 * 64];
    __shared__ float bsm[64];

    const int tid = threadIdx.x;
    const int r0  = blockIdx.x * 64;
    const int bb  = r0 >> 12;
    const int l0  = r0 & 4095;

    {   // zero (pads must stay 0 for the k=64..95 MFMA step)
        const u16x8 z = {0,0,0,0,0,0,0,0};
        for (int i = tid; i < (64 * 104) / 8; i += 256) {
            ((u16x8*)xs)[i] = z;  ((u16x8*)wt)[i] = z;
        }
    }
    __syncthreads();

    // stage x -> bf16 LDS, coalesced
    for (int i = tid; i < 64 * 65; i += 256) {
        const int row = i / 65, col = i - row * 65;
        __hip_bfloat16 v = __float2bfloat16(x[(size_t)r0 * 65 + i]);
        xs[row * 104 + col] = *(unsigned short*)&v;
    }

    const float* Wp[3] = {Wq, Wk, Wv};
    const float* bp[3] = {bq, bk, bv};

    const int w = tid >> 6, lane = tid & 63, li = lane & 15, lg = lane >> 4;
    const int rb = w * 16;

#pragma unroll
    for (int p = 0; p < 3; ++p) {
        __syncthreads();                       // prior pass done with wt/bounce
        for (int i = tid; i < 65 * 64; i += 256) {
            const int k = i >> 6, cc = i & 63;
            __hip_bfloat16 v = __float2bfloat16(Wp[p][i]);
            wt[cc * 104 + k] = *(unsigned short*)&v;
        }
        if (tid < 64) bsm[tid] = bp[p][tid];
        __syncthreads();

        f32x4 acc[4];
#pragma unroll
        for (int j = 0; j < 4; ++j) {
            const float bv_ = bsm[j * 16 + li];
            acc[j] = (f32x4){bv_, bv_, bv_, bv_};
        }
#pragma unroll
        for (int ks = 0; ks < 3; ++ks) {
            const bf16x8 a = __builtin_bit_cast(bf16x8,
                *(const u16x8*)&xs[(rb + li) * 104 + ks * 32 + 8 * lg]);
#pragma unroll
            for (int j = 0; j < 4; ++j) {
                const bf16x8 bf = __builtin_bit_cast(bf16x8,
                    *(const u16x8*)&wt[(j * 16 + li) * 104 + ks * 32 + 8 * lg]);
                acc[j] = __builtin_amdgcn_mfma_f32_16x16x32_bf16(a, bf, acc[j], 0, 0, 0);
            }
        }

        // acc -> bounce (bf16), D row = rb + lg*4 + r, col = j*16 + li
        const float scale = (p == 0) ? (1.4426950408889634f / 8.06225774829855f) : 1.0f;
#pragma unroll
        for (int j = 0; j < 4; ++j)
#pragma unroll
            for (int r = 0; r < 4; ++r) {
                __hip_bfloat16 hv = __float2bfloat16(acc[j][r] * scale);
                bounce[(rb + lg * 4 + r) * 64 + j * 16 + li] = *(unsigned short*)&hv;
            }
        __syncthreads();

        if (p == 0) {
            const int row = tid >> 2, col = (tid & 3) * 16;
            unsigned short* op = qo + (size_t)(r0 + row) * 64 + col;
            *(u16x8*)op       = *(const u16x8*)&bounce[row * 64 + col];
            *(u16x8*)(op + 8) = *(const u16x8*)&bounce[row * 64 + col + 8];
        } else if (p == 1) {
#pragma unroll
            for (int e = 0; e < 2; ++e) {
                const int pi = tid * 2 + e;
                const int row = pi >> 3, s = pi & 7;
                const int l = l0 + row;
                const u16x8 piece = *(const u16x8*)&bounce[row * 64 + ((s ^ (row & 7)) << 3)];
                *(u16x8*)(Kp + (size_t)(bb * 128 + (l >> 5)) * 2048 + (l & 31) * 64 + s * 8) = piece;
            }
        } else {
#pragma unroll
            for (int e = 0; e < 2; ++e) {
                const int pi = tid * 2 + e;
                const int t32 = pi >> 8, rem = pi & 255;
                const int dv = rem >> 2, cp = rem & 3;
                const int u = cp ^ ((dv >> 1) & 3);
                const int m = u >> 1, h = u & 1;
                u16x8 piece;
#pragma unroll
                for (int j = 0; j < 8; ++j) {
                    const int kv = m * 16 + h * 4 + (j & 3) + 8 * (j >> 2);
                    piece[j] = bounce[(t32 * 32 + kv) * 64 + dv];
                }
                *(u16x8*)(Vp + (size_t)(bb * 128 + (l0 >> 5) + t32) * 2048 + dv * 32 + cp * 8) = piece;
            }
        }
    }
}

// ---------------------------------------------------------------------------
// Kernel 2: causal flash attention, 32x32x16 MFMA, fixed softmax base M=8.
// 3-deep LDS pipeline (issue-to-consume = 2 tiles covers HBM latency);
// steady-state vmcnt(8); all partial/output stores non-temporal so the
// streaming traffic does not evict the L2-resident K/V images.
// ---------------------------------------------------------------------------
__global__ __launch_bounds__(256, 3) void attn(
    const unsigned short* __restrict__ Q,
    const unsigned short* __restrict__ Kp,
    const unsigned short* __restrict__ Vp,
    float* __restrict__ O,
    unsigned short* __restrict__ Op,
    float* __restrict__ Lp)
{
    __shared__ __align__(16) unsigned short SM[3][8192];  // K 0..4095 | V 4096..8191

    const int tid  = threadIdx.x;
    const int w    = tid >> 6;
    const int lane = tid & 63;
    const int li32 = lane & 31;
    const int h    = lane >> 5;

    const int b = blockIdx.x & 7;
    const int p = 143 - (blockIdx.x >> 3);   // heavy chunks first
    int g = 0;
    while (2 * (g + 1) * (g + 2) <= p) ++g;
    const int id2 = p - 2 * g * (g + 1);
    const int qq  = id2 / (g + 1);
    const int qb  = 4 * g + qq;
    const int c   = id2 - qq * (g + 1);

    const int q0    = qb * 128;
    const int kv0   = c << 9;
    const int kvend = (kv0 + 512 < q0 + 128) ? kv0 + 512 : q0 + 128;
    const int ntl   = (kvend - kv0) >> 6;
    const int q0w   = q0 + w * 32;
    const int q     = q0w + li32;

    const size_t base = (size_t)b * L_ * DH;
    const unsigned short* KpB = Kp + ((size_t)(b * 128) + (kv0 >> 5)) * 2048;
    const unsigned short* VpB = Vp + ((size_t)(b * 128) + (kv0 >> 5)) * 2048;

    auto stage_t = [&](int buf, int t) {
        const unsigned short* ksrc = KpB + (size_t)t * 4096 + w * 512 + lane * 8;
        const unsigned short* vsrc = VpB + (size_t)t * 4096 + w * 512 + lane * 8;
        unsigned short* kdst = &SM[buf][0]    + w * 512;
        unsigned short* vdst = &SM[buf][4096] + w * 512;
#pragma unroll
        for (int j2 = 0; j2 < 2; ++j2) {
            __builtin_amdgcn_global_load_lds(
                (const __attribute__((address_space(1))) void*)(ksrc + j2 * 2048),
                (__attribute__((address_space(3))) void*)(kdst + j2 * 2048), 16, 0, 0);
            __builtin_amdgcn_global_load_lds(
                (const __attribute__((address_space(1))) void*)(vsrc + j2 * 2048),
                (__attribute__((address_space(3))) void*)(vdst + j2 * 2048), 16, 0, 0);
        }
    };

    // 3-deep prologue: DMA starts before anything else
    stage_t(0, 0);
    if (ntl > 1) stage_t(1, 1);
    if (ntl > 2) stage_t(2, 2);

    // Q fragments: B-operand, col = q, slot (h,j) -> d = ks*16 + h*8 + j
    bf16x8 qf[4];
#pragma unroll
    for (int ks = 0; ks < 4; ++ks)
        qf[ks] = __builtin_bit_cast(bf16x8,
            *(const u16x8*)(Q + base + (size_t)q * DH + ks * 16 + h * 8));

    // all-ones B fragment for the row-sum MFMA
    u16x8 ou;
#pragma unroll
    for (int i = 0; i < 8; ++i) ou[i] = 0x3F80;
    const bf16x8 ones = __builtin_bit_cast(bf16x8, ou);

    f32x16 o0, o1, l_acc;
#pragma unroll
    for (int r = 0; r < 16; ++r) { o0[r] = 0.0f; o1[r] = 0.0f; l_acc[r] = 0.0f; }

    int buf = 0;
    for (int t = 0; t < ntl; ++t) {
        const int rem = ntl - 1 - t;           // prefetched tiles still in flight
        if (rem >= 2)      { asm volatile("s_waitcnt vmcnt(8)" ::: "memory"); }
        else if (rem == 1) { asm volatile("s_waitcnt vmcnt(4)" ::: "memory"); }
        else               { asm volatile("s_waitcnt vmcnt(0)" ::: "memory"); }
        __builtin_amdgcn_s_barrier();

        const int kvb = kv0 + t * 64;
        const unsigned short* SMp = &SM[buf][0];

        if (kvb <= q0w + 31) {
#pragma unroll
            for (int sub = 0; sub < 2; ++sub) {
                const int kvbs = kvb + sub * 32;
                if (sub == 1 && kvbs > q0w + 31) break;
                const int soff = sub * 2048;

                // ---- S^T = K * Q^T (C init = -8: fixed softmax base) ----
                f32x16 s;
#pragma unroll
                for (int r = 0; r < 16; ++r) s[r] = -8.0f;
                __builtin_amdgcn_s_setprio(1);
#pragma unroll
                for (int ks = 0; ks < 4; ++ks) {
                    const bf16x8 kf = __builtin_bit_cast(bf16x8,
                        *(const u16x8*)&SMp[soff + li32 * 64 +
                                            ((((ks << 1) | h) ^ (li32 & 7)) << 3)]);
                    s = __builtin_amdgcn_mfma_f32_32x32x16_bf16(kf, qf[ks], s, 0, 0, 0);
                }
                __builtin_amdgcn_s_setprio(0);

                if (kvbs + 31 > q0w) {       // diagonal subtile: causal mask
#pragma unroll
                    for (int r = 0; r < 16; ++r) {
                        const int kv = kvbs + (r & 3) + ((r >> 2) << 3) + (h << 2);
                        s[r] = (kv > q) ? -1e30f : s[r];
                    }
                }

#pragma unroll
                for (int r = 0; r < 16; ++r) s[r] = __builtin_amdgcn_exp2f(s[r]);

                bf16x8 pf0, pf1;
#pragma unroll
                for (int i = 0; i < 8; ++i) {
                    pf0[i] = (__bf16)s[i];
                    pf1[i] = (__bf16)s[8 + i];
                }

                __builtin_amdgcn_s_setprio(1);
                // ---- row sums via MFMA (l_acc row layout == O row layout) ----
                l_acc = __builtin_amdgcn_mfma_f32_32x32x16_bf16(pf0, ones, l_acc, 0, 0, 0);
                l_acc = __builtin_amdgcn_mfma_f32_32x32x16_bf16(pf1, ones, l_acc, 0, 0, 0);

                // ---- PV ----
                {
                    const int dv = li32;
                    const int c0 = ((0 | h) ^ ((dv >> 1) & 3)) << 3;
                    const int c1 = ((2 | h) ^ ((dv >> 1) & 3)) << 3;
                    const bf16x8 v0 = __builtin_bit_cast(bf16x8,
                        *(const u16x8*)&SMp[4096 + soff + dv * 32 + c0]);
                    const bf16x8 v1 = __builtin_bit_cast(bf16x8,
                        *(const u16x8*)&SMp[4096 + soff + dv * 32 + c1]);
                    o0 = __builtin_amdgcn_mfma_f32_32x32x16_bf16(pf0, v0, o0, 0, 0, 0);
                    o0 = __builtin_amdgcn_mfma_f32_32x32x16_bf16(pf1, v1, o0, 0, 0, 0);
                }
                {
                    const int dv = 32 + li32;
                    const int c0 = ((0 | h) ^ ((dv >> 1) & 3)) << 3;
                    const int c1 = ((2 | h) ^ ((dv >> 1) & 3)) << 3;
                    const bf16x8 v0 = __builtin_bit_cast(bf16x8,
                        *(const u16x8*)&SMp[4096 + soff + dv * 32 + c0]);
                    const bf16x8 v1 = __builtin_bit_cast(bf16x8,
                        *(const u16x8*)&SMp[4096 + soff + dv * 32 + c1]);
                    o1 = __builtin_amdgcn_mfma_f32_32x32x16_bf16(pf0, v0, o1, 0, 0, 0);
                    o1 = __builtin_amdgcn_mfma_f32_32x32x16_bf16(pf1, v1, o1, 0, 0, 0);
                }
                __builtin_amdgcn_s_setprio(0);
            }
        }

        __builtin_amdgcn_s_barrier();          // all waves done with SM[buf]
        if (t + 3 < ntl) stage_t(buf, t + 3);  // refill the just-freed buffer
        buf = (buf == 2) ? 0 : buf + 1;
    }

    // ---- epilogue (non-temporal: keep K/V resident in L2) ----
    if (g == 0) {                  // single chunk: final output
#pragma unroll
        for (int r = 0; r < 16; ++r) {
            const int row = (r & 3) + ((r >> 2) << 3) + (h << 2);
            const float inv = 1.0f / l_acc[r];
            float* orow = O + ((size_t)b * L_ + q0w + row) * DH;
            __builtin_nontemporal_store(o0[r] * inv, orow + li32);
            __builtin_nontemporal_store(o1[r] * inv, orow + 32 + li32);
        }
    } else {
        const int idx = (b * 32 + qb) * 8 + c;
        unsigned short* po = Op + (size_t)idx * 8192;
        float* lp = Lp + (size_t)idx * 128;
#pragma unroll
        for (int r = 0; r < 16; ++r) {
            const int row = (r & 3) + ((r >> 2) << 3) + (h << 2);
            __hip_bfloat16 h0 = __float2bfloat16(o0[r]);
            __hip_bfloat16 h1 = __float2bfloat16(o1[r]);
            __builtin_nontemporal_store(*(unsigned short*)&h0,
                                        po + (w * 32 + row) * 64 + li32);
            __builtin_nontemporal_store(*(unsigned short*)&h1,
                                        po + (w * 32 + row) * 64 + 32 + li32);
            if (li32 == 0) __builtin_nontemporal_store(l_acc[r], lp + w * 32 + row);
        }
    }
}

// ---------------------------------------------------------------------------
// Kernel 3: merge partial chunks (plain sums — shared fixed softmax base).
// Non-temporal throughout (pure streaming).
// ---------------------------------------------------------------------------
__global__ __launch_bounds__(256) void merge(
    const unsigned short* __restrict__ Op,
    const float* __restrict__ Lp,
    float* __restrict__ O)
{
    const int b  = blockIdx.x & 7;
    const int qb = 4 + (blockIdx.x >> 3);
    const int nc = (qb >> 2) + 1;

    const int row = threadIdx.x >> 1;
    const int c0  = (threadIdx.x & 1) * 32;
    const int idx0 = (b * 32 + qb) * 8;

    float acc[32];
#pragma unroll
    for (int j = 0; j < 32; ++j) acc[j] = 0.0f;
    float Lr = 0.0f;

    for (int cc = 0; cc < nc; ++cc) {
        Lr += Lp[(size_t)(idx0 + cc) * 128 + row];
        const unsigned short* pp = Op + (size_t)(idx0 + cc) * 8192 + row * 64 + c0;
#pragma unroll
        for (int j8 = 0; j8 < 4; ++j8) {
            const u16x8 a = __builtin_nontemporal_load((const u16x8*)(pp + j8 * 8));
#pragma unroll
            for (int j = 0; j < 8; ++j) {
                const unsigned int ua = ((unsigned int)a[j]) << 16;
                acc[j8 * 8 + j] += __builtin_bit_cast(float, ua);
            }
        }
    }

    const float inv = 1.0f / Lr;
    float* out = O + ((size_t)b * L_ + qb * 128 + row) * DH + c0;
#pragma unroll
    for (int j4 = 0; j4 < 8; ++j4) {
        f32x4 v;
#pragma unroll
        for (int j = 0; j < 4; ++j) v[j] = acc[j4 * 4 + j] * inv;
        __builtin_nontemporal_store(v, (f32x4*)(out + j4 * 4));
    }
}

// ---------------------------------------------------------------------------
extern "C" void kernel_launch(void* const* d_in, const int* in_sizes, int n_in,
                              void* d_out, int out_size, void* d_ws, size_t ws_size,
                              hipStream_t stream)
{
    const float* x  = (const float*)d_in[0];
    const float* Wq = (const float*)d_in[1];
    const float* bq = (const float*)d_in[2];
    const float* Wk = (const float*)d_in[3];
    const float* bk = (const float*)d_in[4];
    const float* Wv = (const float*)d_in[5];
    const float* bv = (const float*)d_in[6];

    unsigned short* ws16 = (unsigned short*)d_ws;
    unsigned short* qw  = ws16 + QW_OFF;
    unsigned short* kp  = ws16 + KW_OFF;
    unsigned short* vp  = ws16 + VP_OFF;
    unsigned short* Opp = ws16 + OP_OFF;
    float* Lp = (float*)((char*)d_ws + LP_OFFB);

    qkv_proj<<<512, 256, 0, stream>>>(x, Wq, bq, Wk, bk, Wv, bv, qw, kp, vp);
    attn<<<1152, 256, 0, stream>>>(qw, kp, vp, (float*)d_out, Opp, Lp);
    merge<<<224, 256, 0, stream>>>(Opp, Lp, (float*)d_out);
}

// Round 9
// 61.885 us; speedup vs baseline: 1.0655x; 1.0655x over previous
//
#include <hip/hip_runtime.h>
#include <hip/hip_bf16.h>

#define B_  8
#define L_  4096
#define DH  64

typedef __attribute__((ext_vector_type(8)))  __bf16 bf16x8;
typedef __attribute__((ext_vector_type(16))) float  f32x16;
typedef __attribute__((ext_vector_type(4)))  float  f32x4;
typedef __attribute__((ext_vector_type(8)))  unsigned short u16x8;

// workspace offsets (u16 units unless noted)
#define QW_OFF  0u
#define KW_OFF  2097152u      // Kp: swizzled 32-row K images [8][128][2048]
#define VP_OFF  4194304u      // Vp: slot-permuted V images   [8][128][2048]
#define OP_OFF  6291456u      // bf16 partials [8][32][8][128][64]
#define LP_OFFB 46137344u     // byte offset: f32 l partials [8][32][8][128]

// ---------------------------------------------------------------------------
// Kernel 1: MFMA QKV projection (identical to round-5 verified version).
// ---------------------------------------------------------------------------
__global__ __launch_bounds__(256) void qkv_proj(
    const float* __restrict__ x,
    const float* __restrict__ Wq, const float* __restrict__ bq,
    const float* __restrict__ Wk, const float* __restrict__ bk,
    const float* __restrict__ Wv, const float* __restrict__ bv,
    unsigned short* __restrict__ qo,
    unsigned short* __restrict__ Kp,
    unsigned short* __restrict__ Vp)
{
    __shared__ __align__(16) unsigned short xs[64 * 104];
    __shared__ __align__(16) unsigned short wt[64 * 104];
    __shared__ __align__(16) unsigned short bounce[64 * 64];
    __shared__ float bsm[64];

    const int tid = threadIdx.x;
    const int r0  = blockIdx.x * 64;
    const int bb  = r0 >> 12;
    const int l0  = r0 & 4095;

    {   // zero (pads must stay 0 for the k=64..95 MFMA step)
        const u16x8 z = {0,0,0,0,0,0,0,0};
        for (int i = tid; i < (64 * 104) / 8; i += 256) {
            ((u16x8*)xs)[i] = z;  ((u16x8*)wt)[i] = z;
        }
    }
    __syncthreads();

    // stage x -> bf16 LDS, coalesced
    for (int i = tid; i < 64 * 65; i += 256) {
        const int row = i / 65, col = i - row * 65;
        __hip_bfloat16 v = __float2bfloat16(x[(size_t)r0 * 65 + i]);
        xs[row * 104 + col] = *(unsigned short*)&v;
    }

    const float* Wp[3] = {Wq, Wk, Wv};
    const float* bp[3] = {bq, bk, bv};

    const int w = tid >> 6, lane = tid & 63, li = lane & 15, lg = lane >> 4;
    const int rb = w * 16;

#pragma unroll
    for (int p = 0; p < 3; ++p) {
        __syncthreads();                       // prior pass done with wt/bounce
        for (int i = tid; i < 65 * 64; i += 256) {
            const int k = i >> 6, cc = i & 63;
            __hip_bfloat16 v = __float2bfloat16(Wp[p][i]);
            wt[cc * 104 + k] = *(unsigned short*)&v;
        }
        if (tid < 64) bsm[tid] = bp[p][tid];
        __syncthreads();

        f32x4 acc[4];
#pragma unroll
        for (int j = 0; j < 4; ++j) {
            const float bv_ = bsm[j * 16 + li];
            acc[j] = (f32x4){bv_, bv_, bv_, bv_};
        }
#pragma unroll
        for (int ks = 0; ks < 3; ++ks) {
            const bf16x8 a = __builtin_bit_cast(bf16x8,
                *(const u16x8*)&xs[(rb + li) * 104 + ks * 32 + 8 * lg]);
#pragma unroll
            for (int j = 0; j < 4; ++j) {
                const bf16x8 bf = __builtin_bit_cast(bf16x8,
                    *(const u16x8*)&wt[(j * 16 + li) * 104 + ks * 32 + 8 * lg]);
                acc[j] = __builtin_amdgcn_mfma_f32_16x16x32_bf16(a, bf, acc[j], 0, 0, 0);
            }
        }

        // acc -> bounce (bf16), D row = rb + lg*4 + r, col = j*16 + li
        const float scale = (p == 0) ? (1.4426950408889634f / 8.06225774829855f) : 1.0f;
#pragma unroll
        for (int j = 0; j < 4; ++j)
#pragma unroll
            for (int r = 0; r < 4; ++r) {
                __hip_bfloat16 hv = __float2bfloat16(acc[j][r] * scale);
                bounce[(rb + lg * 4 + r) * 64 + j * 16 + li] = *(unsigned short*)&hv;
            }
        __syncthreads();

        if (p == 0) {
            const int row = tid >> 2, col = (tid & 3) * 16;
            unsigned short* op = qo + (size_t)(r0 + row) * 64 + col;
            *(u16x8*)op       = *(const u16x8*)&bounce[row * 64 + col];
            *(u16x8*)(op + 8) = *(const u16x8*)&bounce[row * 64 + col + 8];
        } else if (p == 1) {
#pragma unroll
            for (int e = 0; e < 2; ++e) {
                const int pi = tid * 2 + e;
                const int row = pi >> 3, s = pi & 7;
                const int l = l0 + row;
                const u16x8 piece = *(const u16x8*)&bounce[row * 64 + ((s ^ (row & 7)) << 3)];
                *(u16x8*)(Kp + (size_t)(bb * 128 + (l >> 5)) * 2048 + (l & 31) * 64 + s * 8) = piece;
            }
        } else {
#pragma unroll
            for (int e = 0; e < 2; ++e) {
                const int pi = tid * 2 + e;
                const int t32 = pi >> 8, rem = pi & 255;
                const int dv = rem >> 2, cp = rem & 3;
                const int u = cp ^ ((dv >> 1) & 3);
                const int m = u >> 1, h = u & 1;
                u16x8 piece;
#pragma unroll
                for (int j = 0; j < 8; ++j) {
                    const int kv = m * 16 + h * 4 + (j & 3) + 8 * (j >> 2);
                    piece[j] = bounce[(t32 * 32 + kv) * 64 + dv];
                }
                *(u16x8*)(Vp + (size_t)(bb * 128 + (l0 >> 5) + t32) * 2048 + dv * 32 + cp * 8) = piece;
            }
        }
    }
}

// ---------------------------------------------------------------------------
// Kernel 2: causal flash attention, 32x32x16 MFMA, fixed softmax base M=8.
// Blocks of 2 waves x 64 q-rows. Each wave computes TWO 32x32 row-blocks
// that SHARE the K and V LDS fragments -> LDS-read pipe pressure halved,
// per-wave ILP doubled. 2-buffer pipeline, counted vmcnt, plain stores.
// ---------------------------------------------------------------------------
__global__ __launch_bounds__(128, 2) void attn(
    const unsigned short* __restrict__ Q,
    const unsigned short* __restrict__ Kp,
    const unsigned short* __restrict__ Vp,
    float* __restrict__ O,
    unsigned short* __restrict__ Op,
    float* __restrict__ Lp)
{
    __shared__ __align__(16) unsigned short SM[2][8192];  // K 0..4095 | V 4096..8191

    const int tid  = threadIdx.x;
    const int w    = tid >> 6;          // wave 0..1
    const int lane = tid & 63;
    const int li32 = lane & 31;
    const int h    = lane >> 5;

    const int b = blockIdx.x & 7;
    const int p = 143 - (blockIdx.x >> 3);   // heavy chunks first
    int g = 0;
    while (2 * (g + 1) * (g + 2) <= p) ++g;
    const int id2 = p - 2 * g * (g + 1);
    const int qq  = id2 / (g + 1);
    const int qb  = 4 * g + qq;
    const int c   = id2 - qq * (g + 1);

    const int q0    = qb * 128;
    const int kv0   = c << 9;
    const int kvend = (kv0 + 512 < q0 + 128) ? kv0 + 512 : q0 + 128;
    const int ntl   = (kvend - kv0) >> 6;
    const int q0w   = q0 + w * 64;           // wave owns 64 q rows

    const size_t base = (size_t)b * L_ * DH;
    const unsigned short* KpB = Kp + ((size_t)(b * 128) + (kv0 >> 5)) * 2048;
    const unsigned short* VpB = Vp + ((size_t)(b * 128) + (kv0 >> 5)) * 2048;

    // stage one 64-kv tile (16 KB): each of 2 waves stages half of K and V.
    auto stage_t = [&](int buf, int t) {
        const unsigned short* kt = KpB + (size_t)t * 4096 + w * 2048 + lane * 8;
        const unsigned short* vt = VpB + (size_t)t * 4096 + w * 2048 + lane * 8;
        unsigned short* kd = &SM[buf][0]    + w * 2048;
        unsigned short* vd = &SM[buf][4096] + w * 2048;
#pragma unroll
        for (int j = 0; j < 4; ++j) {
            __builtin_amdgcn_global_load_lds(
                (const __attribute__((address_space(1))) void*)(kt + j * 512),
                (__attribute__((address_space(3))) void*)(kd + j * 512), 16, 0, 0);
            __builtin_amdgcn_global_load_lds(
                (const __attribute__((address_space(1))) void*)(vt + j * 512),
                (__attribute__((address_space(3))) void*)(vd + j * 512), 16, 0, 0);
        }
    };

    stage_t(0, 0);
    if (ntl > 1) stage_t(1, 1);

    // Q fragments for both row-blocks: B-operand, col = q, slot (h,j) -> d = ks*16+h*8+j
    bf16x8 qf[2][4];
#pragma unroll
    for (int i = 0; i < 2; ++i)
#pragma unroll
        for (int ks = 0; ks < 4; ++ks)
            qf[i][ks] = __builtin_bit_cast(bf16x8,
                *(const u16x8*)(Q + base + (size_t)(q0w + i * 32 + li32) * DH
                                + ks * 16 + h * 8));

    // all-ones B fragment for the row-sum MFMA
    u16x8 ou;
#pragma unroll
    for (int i = 0; i < 8; ++i) ou[i] = 0x3F80;
    const bf16x8 ones = __builtin_bit_cast(bf16x8, ou);

    f32x16 o00, o01, o10, o11, l0a, l1a;
#pragma unroll
    for (int r = 0; r < 16; ++r) {
        o00[r] = 0.0f; o01[r] = 0.0f; o10[r] = 0.0f; o11[r] = 0.0f;
        l0a[r] = 0.0f; l1a[r] = 0.0f;
    }

    for (int t = 0; t < ntl; ++t) {
        if (t + 1 < ntl) { asm volatile("s_waitcnt vmcnt(8)" ::: "memory"); }
        else             { asm volatile("s_waitcnt vmcnt(0)" ::: "memory"); }
        __builtin_amdgcn_s_barrier();

        const int kvbase = kv0 + t * 64;
        const unsigned short* SMp = &SM[t & 1][0];

        if (kvbase <= q0w + 63) {
#pragma unroll
            for (int sub = 0; sub < 2; ++sub) {
                const int kvbs = kvbase + sub * 32;
                if (sub == 1 && kvbs > q0w + 63) break;
                const int soff = sub * 2048;
                const bool a0 = (kvbs <= q0w + 31);   // row-block 0 active

                // ---- shared K fragments (4 b128, swizzled conflict-free) ----
                bf16x8 kf[4];
#pragma unroll
                for (int ks = 0; ks < 4; ++ks)
                    kf[ks] = __builtin_bit_cast(bf16x8,
                        *(const u16x8*)&SMp[soff + li32 * 64 +
                                            ((((ks << 1) | h) ^ (li32 & 7)) << 3)]);

                // ---- S^T = K * Q^T for both row-blocks (C init = -8) ----
                f32x16 s0, s1;
#pragma unroll
                for (int r = 0; r < 16; ++r) { s0[r] = -8.0f; s1[r] = -8.0f; }
                __builtin_amdgcn_s_setprio(1);
#pragma unroll
                for (int ks = 0; ks < 4; ++ks)
                    s1 = __builtin_amdgcn_mfma_f32_32x32x16_bf16(kf[ks], qf[1][ks], s1, 0, 0, 0);
                if (a0) {
#pragma unroll
                    for (int ks = 0; ks < 4; ++ks)
                        s0 = __builtin_amdgcn_mfma_f32_32x32x16_bf16(kf[ks], qf[0][ks], s0, 0, 0, 0);
                }
                __builtin_amdgcn_s_setprio(0);

                // ---- causal mask (diagonal subtiles only) ----
                if (kvbs + 31 > q0w + 32) {
                    const int q1 = q0w + 32 + li32;
#pragma unroll
                    for (int r = 0; r < 16; ++r) {
                        const int kv = kvbs + (r & 3) + ((r >> 2) << 3) + (h << 2);
                        s1[r] = (kv > q1) ? -1e30f : s1[r];
                    }
                }
                if (a0 && kvbs + 31 > q0w) {
                    const int qv = q0w + li32;
#pragma unroll
                    for (int r = 0; r < 16; ++r) {
                        const int kv = kvbs + (r & 3) + ((r >> 2) << 3) + (h << 2);
                        s0[r] = (kv > qv) ? -1e30f : s0[r];
                    }
                }

                // ---- exp2 + bf16 fragments ----
#pragma unroll
                for (int r = 0; r < 16; ++r) s1[r] = __builtin_amdgcn_exp2f(s1[r]);
                bf16x8 pf1a, pf1b;
#pragma unroll
                for (int i = 0; i < 8; ++i) { pf1a[i] = (__bf16)s1[i]; pf1b[i] = (__bf16)s1[8 + i]; }
                bf16x8 pf0a, pf0b;
                if (a0) {
#pragma unroll
                    for (int r = 0; r < 16; ++r) s0[r] = __builtin_amdgcn_exp2f(s0[r]);
#pragma unroll
                    for (int i = 0; i < 8; ++i) { pf0a[i] = (__bf16)s0[i]; pf0b[i] = (__bf16)s0[8 + i]; }
                }

                // ---- shared V fragments (4 b128) ----
                const int dv0 = li32, dv1 = 32 + li32;
                const bf16x8 v00 = __builtin_bit_cast(bf16x8,
                    *(const u16x8*)&SMp[4096 + soff + dv0 * 32 + (((0 | h) ^ ((dv0 >> 1) & 3)) << 3)]);
                const bf16x8 v01 = __builtin_bit_cast(bf16x8,
                    *(const u16x8*)&SMp[4096 + soff + dv0 * 32 + (((2 | h) ^ ((dv0 >> 1) & 3)) << 3)]);
                const bf16x8 v10 = __builtin_bit_cast(bf16x8,
                    *(const u16x8*)&SMp[4096 + soff + dv1 * 32 + (((0 | h) ^ ((dv1 >> 1) & 3)) << 3)]);
                const bf16x8 v11 = __builtin_bit_cast(bf16x8,
                    *(const u16x8*)&SMp[4096 + soff + dv1 * 32 + (((2 | h) ^ ((dv1 >> 1) & 3)) << 3)]);

                __builtin_amdgcn_s_setprio(1);
                // ---- row sums + PV, row-block 1 ----
                l1a = __builtin_amdgcn_mfma_f32_32x32x16_bf16(pf1a, ones, l1a, 0, 0, 0);
                l1a = __builtin_amdgcn_mfma_f32_32x32x16_bf16(pf1b, ones, l1a, 0, 0, 0);
                o10 = __builtin_amdgcn_mfma_f32_32x32x16_bf16(pf1a, v00, o10, 0, 0, 0);
                o10 = __builtin_amdgcn_mfma_f32_32x32x16_bf16(pf1b, v01, o10, 0, 0, 0);
                o11 = __builtin_amdgcn_mfma_f32_32x32x16_bf16(pf1a, v10, o11, 0, 0, 0);
                o11 = __builtin_amdgcn_mfma_f32_32x32x16_bf16(pf1b, v11, o11, 0, 0, 0);
                // ---- row-block 0 (shares kf/v fragments) ----
                if (a0) {
                    l0a = __builtin_amdgcn_mfma_f32_32x32x16_bf16(pf0a, ones, l0a, 0, 0, 0);
                    l0a = __builtin_amdgcn_mfma_f32_32x32x16_bf16(pf0b, ones, l0a, 0, 0, 0);
                    o00 = __builtin_amdgcn_mfma_f32_32x32x16_bf16(pf0a, v00, o00, 0, 0, 0);
                    o00 = __builtin_amdgcn_mfma_f32_32x32x16_bf16(pf0b, v01, o00, 0, 0, 0);
                    o01 = __builtin_amdgcn_mfma_f32_32x32x16_bf16(pf0a, v10, o01, 0, 0, 0);
                    o01 = __builtin_amdgcn_mfma_f32_32x32x16_bf16(pf0b, v11, o01, 0, 0, 0);
                }
                __builtin_amdgcn_s_setprio(0);
            }
        }

        __builtin_amdgcn_s_barrier();          // both waves done with SM[t&1]
        if (t + 2 < ntl) stage_t(t & 1, t + 2);
    }

    // ---- epilogue.  O C/D: col = dv, row = (r&3)+8*(r>>2)+4h ----
    if (g == 0) {                  // single chunk: final output
#pragma unroll
        for (int r = 0; r < 16; ++r) {
            const int row = (r & 3) + ((r >> 2) << 3) + (h << 2);
            const float inv0 = 1.0f / l0a[r];
            const float inv1 = 1.0f / l1a[r];
            float* orow0 = O + ((size_t)b * L_ + q0w + row) * DH;
            float* orow1 = O + ((size_t)b * L_ + q0w + 32 + row) * DH;
            orow0[li32]      = o00[r] * inv0;
            orow0[32 + li32] = o01[r] * inv0;
            orow1[li32]      = o10[r] * inv1;
            orow1[32 + li32] = o11[r] * inv1;
        }
    } else {
        const int idx = (b * 32 + qb) * 8 + c;
        unsigned short* po = Op + (size_t)idx * 8192;
        float* lp = Lp + (size_t)idx * 128;
#pragma unroll
        for (int r = 0; r < 16; ++r) {
            const int rr = (r & 3) + ((r >> 2) << 3) + (h << 2);
            const int row0 = w * 64 + rr;
            const int row1 = w * 64 + 32 + rr;
            __hip_bfloat16 h00 = __float2bfloat16(o00[r]);
            __hip_bfloat16 h01 = __float2bfloat16(o01[r]);
            __hip_bfloat16 h10 = __float2bfloat16(o10[r]);
            __hip_bfloat16 h11 = __float2bfloat16(o11[r]);
            po[row0 * 64 + li32]      = *(unsigned short*)&h00;
            po[row0 * 64 + 32 + li32] = *(unsigned short*)&h01;
            po[row1 * 64 + li32]      = *(unsigned short*)&h10;
            po[row1 * 64 + 32 + li32] = *(unsigned short*)&h11;
            if (li32 == 0) { lp[row0] = l0a[r]; lp[row1] = l1a[r]; }
        }
    }
}

// ---------------------------------------------------------------------------
// Kernel 3: merge partial chunks (plain sums — shared fixed softmax base).
// ---------------------------------------------------------------------------
__global__ __launch_bounds__(256) void merge(
    const unsigned short* __restrict__ Op,
    const float* __restrict__ Lp,
    float* __restrict__ O)
{
    const int b  = blockIdx.x & 7;
    const int qb = 4 + (blockIdx.x >> 3);
    const int nc = (qb >> 2) + 1;

    const int row = threadIdx.x >> 1;
    const int c0  = (threadIdx.x & 1) * 32;
    const int idx0 = (b * 32 + qb) * 8;

    float acc[32];
#pragma unroll
    for (int j = 0; j < 32; ++j) acc[j] = 0.0f;
    float Lr = 0.0f;

    for (int cc = 0; cc < nc; ++cc) {
        Lr += Lp[(size_t)(idx0 + cc) * 128 + row];
        const unsigned short* pp = Op + (size_t)(idx0 + cc) * 8192 + row * 64 + c0;
#pragma unroll
        for (int j8 = 0; j8 < 4; ++j8) {
            const u16x8 a = *(const u16x8*)(pp + j8 * 8);
#pragma unroll
            for (int j = 0; j < 8; ++j) {
                const unsigned int ua = ((unsigned int)a[j]) << 16;
                acc[j8 * 8 + j] += __builtin_bit_cast(float, ua);
            }
        }
    }

    const float inv = 1.0f / Lr;
    float* out = O + ((size_t)b * L_ + qb * 128 + row) * DH + c0;
#pragma unroll
    for (int j4 = 0; j4 < 8; ++j4) {
        f32x4 v;
#pragma unroll
        for (int j = 0; j < 4; ++j) v[j] = acc[j4 * 4 + j] * inv;
        *(f32x4*)(out + j4 * 4) = v;
    }
}

// ---------------------------------------------------------------------------
extern "C" void kernel_launch(void* const* d_in, const int* in_sizes, int n_in,
                              void* d_out, int out_size, void* d_ws, size_t ws_size,
                              hipStream_t stream)
{
    const float* x  = (const float*)d_in[0];
    const float* Wq = (const float*)d_in[1];
    const float* bq = (const float*)d_in[2];
    const float* Wk = (const float*)d_in[3];
    const float* bk = (const float*)d_in[4];
    const float* Wv = (const float*)d_in[5];
    const float* bv = (const float*)d_in[6];

    unsigned short* ws16 = (unsigned short*)d_ws;
    unsigned short* qw  = ws16 + QW_OFF;
    unsigned short* kp  = ws16 + KW_OFF;
    unsigned short* vp  = ws16 + VP_OFF;
    unsigned short* Opp = ws16 + OP_OFF;
    float* Lp = (float*)((char*)d_ws + LP_OFFB);

    qkv_proj<<<512, 256, 0, stream>>>(x, Wq, bq, Wk, bk, Wv, bv, qw, kp, vp);
    attn<<<1152, 128, 0, stream>>>(qw, kp, vp, (float*)d_out, Opp, Lp);
    merge<<<224, 256, 0, stream>>>(Opp, Lp, (float*)d_out);
}

// Round 10
// 60.642 us; speedup vs baseline: 1.0873x; 1.0205x over previous
//
#include <hip/hip_runtime.h>
#include <hip/hip_bf16.h>

#define B_  8
#define L_  4096
#define DH  64

typedef __attribute__((ext_vector_type(8)))  __bf16 bf16x8;
typedef __attribute__((ext_vector_type(16))) float  f32x16;
typedef __attribute__((ext_vector_type(4)))  float  f32x4;
typedef __attribute__((ext_vector_type(8)))  unsigned short u16x8;

// workspace offsets (u16 units unless noted)
#define QW_OFF  0u
#define KW_OFF  2097152u      // Kp: swizzled 32-row K images [8][128][2048]
#define VP_OFF  4194304u      // Vp: slot-permuted V images   [8][128][2048]
#define OP_OFF  6291456u      // bf16 partials [8][32][8][128][64]
#define LP_OFFB 46137344u     // byte offset: f32 l partials [8][32][8][128]
#define WT_OFFB 47185920u     // byte offset: bf16 WT [3][64][96] (pre-scaled)
#define BS_OFFB 47222784u     // byte offset: f32 biases [3][64] (pre-scaled)

// ---------------------------------------------------------------------------
// Kernel 0: prep — transpose W into WT[3][64][96] bf16 (k padded to 96,
// Wq/bq pre-scaled by log2e/sqrt(65)), biases to f32 [3][64].
// ---------------------------------------------------------------------------
__global__ __launch_bounds__(256) void prep(
    const float* __restrict__ Wq, const float* __restrict__ bq,
    const float* __restrict__ Wk, const float* __restrict__ bk,
    const float* __restrict__ Wv, const float* __restrict__ bv,
    unsigned short* __restrict__ WT, float* __restrict__ bias_s)
{
    const int p = blockIdx.x;
    const float* W  = (p == 0) ? Wq : (p == 1) ? Wk : Wv;
    const float* bb = (p == 0) ? bq : (p == 1) ? bk : bv;
    const float scale = (p == 0) ? (1.4426950408889634f / 8.06225774829855f) : 1.0f;

    const int c  = threadIdx.x & 63;
    const int kq = threadIdx.x >> 6;
#pragma unroll
    for (int kk = 0; kk < 24; ++kk) {
        const int k = kq * 24 + kk;
        const float v = (k < 65) ? W[k * 64 + c] * scale : 0.0f;
        __hip_bfloat16 h = __float2bfloat16(v);
        WT[(p * 64 + c) * 96 + k] = *(unsigned short*)&h;
    }
    if (threadIdx.x < 64) bias_s[p * 64 + threadIdx.x] = bb[threadIdx.x] * scale;
}

// ---------------------------------------------------------------------------
// Kernel 1: MFMA QKV projection. W fragments read straight from global WT
// (same addresses for every block -> L1/L2 broadcast); LDS holds only the
// x tile + bounce buffer (21.5 KB -> ~7 blocks/CU).
// Outputs identical layouts to the round-5 verified version:
//   qo row-major; Kp swizzled 32-row images; Vp slot-permuted images.
// ---------------------------------------------------------------------------
__global__ __launch_bounds__(256) void qkv_proj(
    const float* __restrict__ x,
    const unsigned short* __restrict__ WT,
    const float* __restrict__ bias_s,
    unsigned short* __restrict__ qo,
    unsigned short* __restrict__ Kp,
    unsigned short* __restrict__ Vp)
{
    __shared__ __align__(16) unsigned short xs[64 * 104];
    __shared__ __align__(16) unsigned short bounce[64 * 64];

    const int tid = threadIdx.x;
    const int r0  = blockIdx.x * 64;
    const int bb  = r0 >> 12;
    const int l0  = r0 & 4095;

    {   // zero xs (pads k=65..103 must be 0)
        const u16x8 z = {0,0,0,0,0,0,0,0};
        for (int i = tid; i < (64 * 104) / 8; i += 256) ((u16x8*)xs)[i] = z;
    }
    __syncthreads();

    // stage x -> bf16 LDS, coalesced
    for (int i = tid; i < 64 * 65; i += 256) {
        const int row = i / 65, col = i - row * 65;
        __hip_bfloat16 v = __float2bfloat16(x[(size_t)r0 * 65 + i]);
        xs[row * 104 + col] = *(unsigned short*)&v;
    }

    const int w = tid >> 6, lane = tid & 63, li = lane & 15, lg = lane >> 4;
    const int rb = w * 16;
    __syncthreads();

#pragma unroll
    for (int p = 0; p < 3; ++p) {
        f32x4 acc[4];
#pragma unroll
        for (int j = 0; j < 4; ++j) {
            const float bv_ = bias_s[p * 64 + j * 16 + li];
            acc[j] = (f32x4){bv_, bv_, bv_, bv_};
        }
#pragma unroll
        for (int ks = 0; ks < 3; ++ks) {
            const bf16x8 a = __builtin_bit_cast(bf16x8,
                *(const u16x8*)&xs[(rb + li) * 104 + ks * 32 + 8 * lg]);
#pragma unroll
            for (int j = 0; j < 4; ++j) {
                const bf16x8 bf = __builtin_bit_cast(bf16x8,
                    *(const u16x8*)(WT + (size_t)(p * 64 + j * 16 + li) * 96
                                    + ks * 32 + 8 * lg));
                acc[j] = __builtin_amdgcn_mfma_f32_16x16x32_bf16(a, bf, acc[j], 0, 0, 0);
            }
        }

        __syncthreads();                       // previous epilogue done with bounce
        // acc -> bounce (bf16), D row = rb + lg*4 + r, col = j*16 + li
#pragma unroll
        for (int j = 0; j < 4; ++j)
#pragma unroll
            for (int r = 0; r < 4; ++r) {
                __hip_bfloat16 hv = __float2bfloat16(acc[j][r]);
                bounce[(rb + lg * 4 + r) * 64 + j * 16 + li] = *(unsigned short*)&hv;
            }
        __syncthreads();

        if (p == 0) {
            const int row = tid >> 2, col = (tid & 3) * 16;
            unsigned short* op = qo + (size_t)(r0 + row) * 64 + col;
            *(u16x8*)op       = *(const u16x8*)&bounce[row * 64 + col];
            *(u16x8*)(op + 8) = *(const u16x8*)&bounce[row * 64 + col + 8];
        } else if (p == 1) {
#pragma unroll
            for (int e = 0; e < 2; ++e) {
                const int pi = tid * 2 + e;
                const int row = pi >> 3, s = pi & 7;
                const int l = l0 + row;
                const u16x8 piece = *(const u16x8*)&bounce[row * 64 + ((s ^ (row & 7)) << 3)];
                *(u16x8*)(Kp + (size_t)(bb * 128 + (l >> 5)) * 2048 + (l & 31) * 64 + s * 8) = piece;
            }
        } else {
#pragma unroll
            for (int e = 0; e < 2; ++e) {
                const int pi = tid * 2 + e;
                const int t32 = pi >> 8, rem = pi & 255;
                const int dv = rem >> 2, cp = rem & 3;
                const int u = cp ^ ((dv >> 1) & 3);
                const int m = u >> 1, h = u & 1;
                u16x8 piece;
#pragma unroll
                for (int j = 0; j < 8; ++j) {
                    const int kv = m * 16 + h * 4 + (j & 3) + 8 * (j >> 2);
                    piece[j] = bounce[(t32 * 32 + kv) * 64 + dv];
                }
                *(u16x8*)(Vp + (size_t)(bb * 128 + (l0 >> 5) + t32) * 2048 + dv * 32 + cp * 8) = piece;
            }
        }
    }
}

// ---------------------------------------------------------------------------
// Kernel 2: causal flash attention — round-5 verified version, unchanged.
// 32x32x16 MFMA, fixed softmax base M=8, 4 waves x 32 q, 512-kv chunks,
// 64-wide KV tiles, double-buffered global_load_lds, counted vmcnt.
// ---------------------------------------------------------------------------
__global__ __launch_bounds__(256, 3) void attn(
    const unsigned short* __restrict__ Q,
    const unsigned short* __restrict__ Kp,
    const unsigned short* __restrict__ Vp,
    float* __restrict__ O,
    unsigned short* __restrict__ Op,
    float* __restrict__ Lp)
{
    __shared__ __align__(16) unsigned short SM[2][8192];  // K 0..4095 | V 4096..8191

    const int tid  = threadIdx.x;
    const int w    = tid >> 6;
    const int lane = tid & 63;
    const int li32 = lane & 31;
    const int h    = lane >> 5;

    const int b = blockIdx.x & 7;
    const int p = 143 - (blockIdx.x >> 3);   // heavy chunks first
    int g = 0;
    while (2 * (g + 1) * (g + 2) <= p) ++g;
    const int id2 = p - 2 * g * (g + 1);
    const int qq  = id2 / (g + 1);
    const int qb  = 4 * g + qq;
    const int c   = id2 - qq * (g + 1);

    const int q0    = qb * 128;
    const int kv0   = c << 9;
    const int kvend = (kv0 + 512 < q0 + 128) ? kv0 + 512 : q0 + 128;
    const int ntl   = (kvend - kv0) >> 6;
    const int q0w   = q0 + w * 32;
    const int q     = q0w + li32;

    const size_t base = (size_t)b * L_ * DH;
    const unsigned short* KpB = Kp + ((size_t)(b * 128) + (kv0 >> 5)) * 2048;
    const unsigned short* VpB = Vp + ((size_t)(b * 128) + (kv0 >> 5)) * 2048;

    // Q fragments: B-operand, col = q, slot (h,j) -> d = ks*16 + h*8 + j
    bf16x8 qf[4];
#pragma unroll
    for (int ks = 0; ks < 4; ++ks)
        qf[ks] = __builtin_bit_cast(bf16x8,
            *(const u16x8*)(Q + base + (size_t)q * DH + ks * 16 + h * 8));

    // all-ones B fragment for the row-sum MFMA
    u16x8 ou;
#pragma unroll
    for (int i = 0; i < 8; ++i) ou[i] = 0x3F80;
    const bf16x8 ones = __builtin_bit_cast(bf16x8, ou);

    f32x16 o0, o1, l_acc;
#pragma unroll
    for (int r = 0; r < 16; ++r) { o0[r] = 0.0f; o1[r] = 0.0f; l_acc[r] = 0.0f; }

    auto stage_t = [&](int buf, int t) {
        const unsigned short* ksrc = KpB + (size_t)t * 4096 + w * 512 + lane * 8;
        const unsigned short* vsrc = VpB + (size_t)t * 4096 + w * 512 + lane * 8;
        unsigned short* kdst = &SM[buf][0]    + w * 512;
        unsigned short* vdst = &SM[buf][4096] + w * 512;
#pragma unroll
        for (int j2 = 0; j2 < 2; ++j2) {
            __builtin_amdgcn_global_load_lds(
                (const __attribute__((address_space(1))) void*)(ksrc + j2 * 2048),
                (__attribute__((address_space(3))) void*)(kdst + j2 * 2048), 16, 0, 0);
            __builtin_amdgcn_global_load_lds(
                (const __attribute__((address_space(1))) void*)(vsrc + j2 * 2048),
                (__attribute__((address_space(3))) void*)(vdst + j2 * 2048), 16, 0, 0);
        }
    };

    stage_t(0, 0);
    if (ntl > 1) stage_t(1, 1);

    for (int t = 0; t < ntl; ++t) {
        if (t + 1 < ntl) { asm volatile("s_waitcnt vmcnt(4)" ::: "memory"); }
        else             { asm volatile("s_waitcnt vmcnt(0)" ::: "memory"); }
        __builtin_amdgcn_s_barrier();

        const int kvb = kv0 + t * 64;
        const unsigned short* SMp = &SM[t & 1][0];

        if (kvb <= q0w + 31) {
#pragma unroll
            for (int sub = 0; sub < 2; ++sub) {
                const int kvbs = kvb + sub * 32;
                if (sub == 1 && kvbs > q0w + 31) break;
                const int soff = sub * 2048;

                // ---- S^T = K * Q^T (C init = -8: fixed softmax base) ----
                f32x16 s;
#pragma unroll
                for (int r = 0; r < 16; ++r) s[r] = -8.0f;
#pragma unroll
                for (int ks = 0; ks < 4; ++ks) {
                    const bf16x8 kf = __builtin_bit_cast(bf16x8,
                        *(const u16x8*)&SMp[soff + li32 * 64 +
                                            ((((ks << 1) | h) ^ (li32 & 7)) << 3)]);
                    s = __builtin_amdgcn_mfma_f32_32x32x16_bf16(kf, qf[ks], s, 0, 0, 0);
                }

                if (kvbs + 31 > q0w) {       // diagonal subtile: causal mask
#pragma unroll
                    for (int r = 0; r < 16; ++r) {
                        const int kv = kvbs + (r & 3) + ((r >> 2) << 3) + (h << 2);
                        s[r] = (kv > q) ? -1e30f : s[r];
                    }
                }

#pragma unroll
                for (int r = 0; r < 16; ++r) s[r] = __builtin_amdgcn_exp2f(s[r]);

                bf16x8 pf0, pf1;
#pragma unroll
                for (int i = 0; i < 8; ++i) {
                    pf0[i] = (__bf16)s[i];
                    pf1[i] = (__bf16)s[8 + i];
                }

                // ---- row sums via MFMA (l_acc row layout == O row layout) ----
                l_acc = __builtin_amdgcn_mfma_f32_32x32x16_bf16(pf0, ones, l_acc, 0, 0, 0);
                l_acc = __builtin_amdgcn_mfma_f32_32x32x16_bf16(pf1, ones, l_acc, 0, 0, 0);

                // ---- PV ----
                {
                    const int dv = li32;
                    const int c0 = ((0 | h) ^ ((dv >> 1) & 3)) << 3;
                    const int c1 = ((2 | h) ^ ((dv >> 1) & 3)) << 3;
                    const bf16x8 v0 = __builtin_bit_cast(bf16x8,
                        *(const u16x8*)&SMp[4096 + soff + dv * 32 + c0]);
                    const bf16x8 v1 = __builtin_bit_cast(bf16x8,
                        *(const u16x8*)&SMp[4096 + soff + dv * 32 + c1]);
                    o0 = __builtin_amdgcn_mfma_f32_32x32x16_bf16(pf0, v0, o0, 0, 0, 0);
                    o0 = __builtin_amdgcn_mfma_f32_32x32x16_bf16(pf1, v1, o0, 0, 0, 0);
                }
                {
                    const int dv = 32 + li32;
                    const int c0 = ((0 | h) ^ ((dv >> 1) & 3)) << 3;
                    const int c1 = ((2 | h) ^ ((dv >> 1) & 3)) << 3;
                    const bf16x8 v0 = __builtin_bit_cast(bf16x8,
                        *(const u16x8*)&SMp[4096 + soff + dv * 32 + c0]);
                    const bf16x8 v1 = __builtin_bit_cast(bf16x8,
                        *(const u16x8*)&SMp[4096 + soff + dv * 32 + c1]);
                    o1 = __builtin_amdgcn_mfma_f32_32x32x16_bf16(pf0, v0, o1, 0, 0, 0);
                    o1 = __builtin_amdgcn_mfma_f32_32x32x16_bf16(pf1, v1, o1, 0, 0, 0);
                }
            }
        }

        __builtin_amdgcn_s_barrier();
        if (t + 2 < ntl) stage_t(t & 1, t + 2);
    }

    // ---- epilogue.  O C/D: col = dv, row = (r&3)+8*(r>>2)+4h (same as l_acc) ----
    if (g == 0) {                  // single chunk: final output
#pragma unroll
        for (int r = 0; r < 16; ++r) {
            const int row = (r & 3) + ((r >> 2) << 3) + (h << 2);
            const float inv = 1.0f / l_acc[r];
            float* orow = O + ((size_t)b * L_ + q0w + row) * DH;
            orow[li32]      = o0[r] * inv;
            orow[32 + li32] = o1[r] * inv;
        }
    } else {
        const int idx = (b * 32 + qb) * 8 + c;
        unsigned short* po = Op + (size_t)idx * 8192;
        float* lp = Lp + (size_t)idx * 128;
#pragma unroll
        for (int r = 0; r < 16; ++r) {
            const int row = (r & 3) + ((r >> 2) << 3) + (h << 2);
            __hip_bfloat16 h0 = __float2bfloat16(o0[r]);
            __hip_bfloat16 h1 = __float2bfloat16(o1[r]);
            po[(w * 32 + row) * 64 + li32]      = *(unsigned short*)&h0;
            po[(w * 32 + row) * 64 + 32 + li32] = *(unsigned short*)&h1;
            if (li32 == 0) lp[w * 32 + row] = l_acc[r];
        }
    }
}

// ---------------------------------------------------------------------------
// Kernel 3: merge partial chunks (plain sums — shared fixed softmax base).
// Re-gridded: 896 blocks (4 row-slices per (b,qb)) for 4x the TLP.
// ---------------------------------------------------------------------------
__global__ __launch_bounds__(256) void merge(
    const unsigned short* __restrict__ Op,
    const float* __restrict__ Lp,
    float* __restrict__ O)
{
    const int b     = blockIdx.x & 7;
    const int rest  = blockIdx.x >> 3;
    const int qb    = 4 + (rest >> 2);
    const int slice = rest & 3;
    const int nc    = (qb >> 2) + 1;

    const int row = slice * 32 + (threadIdx.x >> 3);   // 0..127
    const int cg  = (threadIdx.x & 7) * 8;             // col group of 8
    const int idx0 = (b * 32 + qb) * 8;

    float acc[8];
#pragma unroll
    for (int j = 0; j < 8; ++j) acc[j] = 0.0f;
    float Lr = 0.0f;

    for (int cc = 0; cc < nc; ++cc) {
        Lr += Lp[(size_t)(idx0 + cc) * 128 + row];
        const u16x8 a = *(const u16x8*)(Op + (size_t)(idx0 + cc) * 8192 + row * 64 + cg);
#pragma unroll
        for (int j = 0; j < 8; ++j) {
            const unsigned int ua = ((unsigned int)a[j]) << 16;
            acc[j] += __builtin_bit_cast(float, ua);
        }
    }

    const float inv = 1.0f / Lr;
    float* out = O + ((size_t)b * L_ + qb * 128 + row) * DH + cg;
    f32x4 v0, v1;
#pragma unroll
    for (int j = 0; j < 4; ++j) { v0[j] = acc[j] * inv; v1[j] = acc[4 + j] * inv; }
    *(f32x4*)out       = v0;
    *(f32x4*)(out + 4) = v1;
}

// ---------------------------------------------------------------------------
extern "C" void kernel_launch(void* const* d_in, const int* in_sizes, int n_in,
                              void* d_out, int out_size, void* d_ws, size_t ws_size,
                              hipStream_t stream)
{
    const float* x  = (const float*)d_in[0];
    const float* Wq = (const float*)d_in[1];
    const float* bq = (const float*)d_in[2];
    const float* Wk = (const float*)d_in[3];
    const float* bk = (const float*)d_in[4];
    const float* Wv = (const float*)d_in[5];
    const float* bv = (const float*)d_in[6];

    unsigned short* ws16 = (unsigned short*)d_ws;
    unsigned short* qw  = ws16 + QW_OFF;
    unsigned short* kp  = ws16 + KW_OFF;
    unsigned short* vp  = ws16 + VP_OFF;
    unsigned short* Opp = ws16 + OP_OFF;
    float* Lp = (float*)((char*)d_ws + LP_OFFB);
    unsigned short* WT = (unsigned short*)((char*)d_ws + WT_OFFB);
    float* bias_s = (float*)((char*)d_ws + BS_OFFB);

    prep<<<3, 256, 0, stream>>>(Wq, bq, Wk, bk, Wv, bv, WT, bias_s);
    qkv_proj<<<512, 256, 0, stream>>>(x, WT, bias_s, qw, kp, vp);
    attn<<<1152, 256, 0, stream>>>(qw, kp, vp, (float*)d_out, Opp, Lp);
    merge<<<896, 256, 0, stream>>>(Opp, Lp, (float*)d_out);
}